// Round 6
// baseline (413.380 us; speedup 1.0000x reference)
//
#include <hip/hip_runtime.h>
#include <math.h>

#define BATCH 32
#define NN 512
#define DD 256
#define NUMK 4

typedef __attribute__((ext_vector_type(8))) short bf16x8;
typedef __attribute__((ext_vector_type(4))) float f32x4;
typedef __attribute__((ext_vector_type(4))) unsigned short u16x4;

__device__ __forceinline__ float softplusf(float v) { return log1pf(expf(v)); }

__device__ __forceinline__ unsigned enc_key(float v) {
  unsigned u = __float_as_uint(v);
  return (u & 0x80000000u) ? ~u : (u | 0x80000000u);
}
__device__ __forceinline__ float dec_key(unsigned k) {
  return (k & 0x80000000u) ? __uint_as_float(k & 0x7fffffffu) : __uint_as_float(~k);
}
__device__ __forceinline__ unsigned short f2b(float f) {
  unsigned u = __float_as_uint(f);
  unsigned r = (u + 0x7fffu + ((u >> 16) & 1u)) >> 16;
  return (unsigned short)r;
}
__device__ __forceinline__ float b2f(unsigned short h) {
  return __uint_as_float(((unsigned)h) << 16);
}

#define GLDS(gp, lp)                                                   \
  __builtin_amdgcn_global_load_lds(                                    \
      (__attribute__((address_space(1))) void*)(void*)(gp),            \
      (__attribute__((address_space(3))) void*)(lp), 16, 0, 0)

// ---------- prep: xb = bf16(x) [n][d], xTb = bf16(x^T) [d][n]; zero max keys ----------
__global__ __launch_bounds__(256) void k_prep(const float* __restrict__ x,
                                              short* __restrict__ xb,
                                              short* __restrict__ xTb,
                                              unsigned* keys) {
  __shared__ float t[64][65];
  int b = blockIdx.z, n0 = blockIdx.y * 64, d0 = blockIdx.x * 64;
  if (blockIdx.x == 0 && blockIdx.y == 0 && blockIdx.z == 0 && threadIdx.x == 0) {
    keys[0] = 0u; keys[1] = 0u;
  }
  const float* X = x + (size_t)b * NN * DD;
  int col = threadIdx.x & 63, rr = threadIdx.x >> 6;
#pragma unroll
  for (int s = 0; s < 16; ++s) {
    int row = s * 4 + rr;
    float v = X[(size_t)(n0 + row) * DD + d0 + col];
    t[row][col] = v;
    xb[(size_t)b * NN * DD + (size_t)(n0 + row) * DD + d0 + col] = (short)f2b(v);
  }
  __syncthreads();
#pragma unroll
  for (int s = 0; s < 16; ++s) {
    int row = s * 4 + rr;  // d within tile
    xTb[(size_t)b * DD * NN + (size_t)(d0 + row) * NN + n0 + col] = (short)f2b(t[col][row]);
  }
}

// ---------- Gram / V GEMM: 64x64 tile, BK=64, swizzled LDS, batch-major grid ----------
template <int K, int OUTK>
__global__ __launch_bounds__(256) void k_gemm(
    const short* __restrict__ A, size_t sA, int lda,
    const short* __restrict__ Bp, size_t sB, int ldb,
    void* __restrict__ outp, size_t sO, int ldo,
    float scale, unsigned* maxslot) {
  __shared__ short As[64 * 64];
  __shared__ short Bs[64 * 64];
  const int b = blockIdx.x;
  const int m0 = blockIdx.y * 64, n0 = blockIdx.z * 64;
  const int tid = threadIdx.x, wave = tid >> 6, lane = tid & 63;
  const int ln = lane & 15, kg = lane >> 4;
  const int wr = (wave >> 1) * 32, wc = (wave & 1) * 32;
  const short* Ab = A + (size_t)b * sA;
  const short* Bb = Bp + (size_t)b * sB;
  const int srow = lane >> 3;
  const int sslot = lane & 7;

  f32x4 acc[2][2];
#pragma unroll
  for (int i = 0; i < 2; ++i)
#pragma unroll
    for (int j = 0; j < 2; ++j) acc[i][j] = (f32x4){0.f, 0.f, 0.f, 0.f};

  for (int k0 = 0; k0 < K; k0 += 64) {
    __syncthreads();
#pragma unroll
    for (int p = 0; p < 2; ++p) {
      int row = p * 32 + wave * 8 + srow;
      int sg = sslot ^ (row & 7);
      GLDS(Ab + (size_t)(m0 + row) * lda + k0 + sg * 8, &As[(p * 32 + wave * 8) * 64]);
      GLDS(Bb + (size_t)(n0 + row) * ldb + k0 + sg * 8, &Bs[(p * 32 + wave * 8) * 64]);
    }
    __syncthreads();
    bf16x8 af[2][2], bfr[2][2];
#pragma unroll
    for (int i = 0; i < 2; ++i)
#pragma unroll
      for (int kk = 0; kk < 2; ++kk) {
        int rowA = wr + i * 16 + ln;
        af[i][kk] = *(const bf16x8*)&As[rowA * 64 + (((kk * 4 + kg) ^ (rowA & 7)) * 8)];
        int rowB = wc + i * 16 + ln;
        bfr[i][kk] = *(const bf16x8*)&Bs[rowB * 64 + (((kk * 4 + kg) ^ (rowB & 7)) * 8)];
      }
#pragma unroll
    for (int kk = 0; kk < 2; ++kk)
#pragma unroll
      for (int i = 0; i < 2; ++i)
#pragma unroll
        for (int j = 0; j < 2; ++j)
          acc[i][j] = __builtin_amdgcn_mfma_f32_16x16x32_bf16(af[i][kk], bfr[j][kk],
                                                              acc[i][j], 0, 0, 0);
  }

  unsigned short* ot = (unsigned short*)outp + (size_t)b * sO;
  float tmax = -1e30f;
#pragma unroll
  for (int i = 0; i < 2; ++i) {
    int r = m0 + wr + i * 16 + kg * 4;
#pragma unroll
    for (int j = 0; j < 2; ++j) {
      int c = n0 + wc + j * 16 + ln;
      u16x4 pk;
#pragma unroll
      for (int q = 0; q < 4; ++q) {
        float v = acc[i][j][q] * scale;
        if (OUTK == 0) tmax = fmaxf(tmax, v);
        pk[q] = f2b(v);
      }
      *(u16x4*)&ot[(size_t)c * ldo + r] = pk;
    }
  }
  if (OUTK == 0) {
#pragma unroll
    for (int o = 32; o > 0; o >>= 1) tmax = fmaxf(tmax, __shfl_xor(tmax, o));
    __syncthreads();
    float* smf = (float*)As;
    if (lane == 0) smf[wave] = tmax;
    __syncthreads();
    if (tid == 0)
      atomicMax(maxslot, enc_key(fmaxf(fmaxf(smf[0], smf[1]), fmaxf(smf[2], smf[3]))));
  }
}

// ---------- misc: row sums of c2/c1 + scalar params, one launch ----------
__global__ __launch_bounds__(256) void k_misc(const short* __restrict__ c2b,
                                              const short* __restrict__ c1b,
                                              float* __restrict__ r2,
                                              float* __restrict__ s1,
                                              const float* a0p, const float* a1p,
                                              const float* a2p, const float* a3p,
                                              const float* rhop, float* P,
                                              const unsigned* keys) {
  int bid = blockIdx.x;
  int lane = threadIdx.x & 63;
  if (bid < 4096) {
    int row = bid * 4 + (threadIdx.x >> 6);
    bf16x8 v = *(const bf16x8*)(c2b + (size_t)row * 512 + lane * 8);
    float s = 0.f;
#pragma unroll
    for (int q = 0; q < 8; ++q) s += b2f((unsigned short)v[q]);
#pragma unroll
    for (int o = 32; o > 0; o >>= 1) s += __shfl_xor(s, o);
    if (lane == 0) r2[row] = s;
  } else if (bid < 6144) {
    int row = (bid - 4096) * 4 + (threadIdx.x >> 6);
    u16x4 v = *(const u16x4*)(c1b + (size_t)row * 256 + lane * 4);
    float s = 0.f;
#pragma unroll
    for (int q = 0; q < 4; ++q) s += b2f(v[q]);
#pragma unroll
    for (int o = 32; o > 0; o >>= 1) s += __shfl_xor(s, o);
    if (lane == 0) s1[row] = s;
  } else if (threadIdx.x == 0) {
    float M1 = dec_key(keys[0]);
    float M2 = dec_key(keys[1]);
    float lq0 = logf(1.0f / NN + 1e-8f);
    float lp0 = logf(1.0f / DD + 1e-8f);
    float mu = lq0, eta = lp0, z1 = 0.f, z2 = 0.f;
    for (int k = 0; k < NUMK; ++k) {
      float a0 = softplusf(a0p[k]), a1 = softplusf(a1p[k]);
      float a2 = softplusf(a2p[k]), a3 = softplusf(a3p[k]);
      float rho = softplusf(rhop[k]);
      P[0 + k] = a0;
      P[4 + k] = a1 / (M1 * M2);
      P[8 + k] = rho;
      P[12 + k] = mu;
      P[16 + k] = eta;
      float t1 = mu;
      mu = (a2 * lq0 + rho * t1 - z1) / (a2 + rho);
      z1 += rho * (expf(mu) - expf(t1));
      float s1v = eta;
      eta = (a3 * lp0 + rho * s1v - z2) / (a3 + rho);
      z2 += rho * (expf(eta) - expf(s1v));
    }
  }
}

// ---------- iter-0 T-update via rank-1 gw ----------
__global__ __launch_bounds__(256) void k_trow0(const float* __restrict__ x,
                                               const float* __restrict__ r2,
                                               const float* __restrict__ s1,
                                               float* __restrict__ log_t,
                                               short* __restrict__ eT,
                                               const float* __restrict__ P) {
  size_t row = blockIdx.x;  // b*N + n
  int b = (int)(row >> 9);
  const float c0 = logf(1.0f / NN + 1e-8f) + logf(1.0f / DD + 1e-8f);
  float g = P[4] * expf(c0) * r2[row];
  float inv = 1.0f / (P[8] + P[0]);
  float y = (x[row * DD + threadIdx.x] + g * s1[(size_t)b * DD + threadIdx.x]) * inv;
  float m = y;
#pragma unroll
  for (int o = 32; o > 0; o >>= 1) m = fmaxf(m, __shfl_xor(m, o));
  __shared__ float sm[4], ss[4];
  int wv = threadIdx.x >> 6;
  if ((threadIdx.x & 63) == 0) sm[wv] = m;
  __syncthreads();
  m = fmaxf(fmaxf(sm[0], sm[1]), fmaxf(sm[2], sm[3]));
  float sum = expf(y - m);
#pragma unroll
  for (int o = 32; o > 0; o >>= 1) sum += __shfl_xor(sum, o);
  if ((threadIdx.x & 63) == 0) ss[wv] = sum;
  __syncthreads();
  float lse = m + logf(ss[0] + ss[1] + ss[2] + ss[3]);
  float lt = P[12] + y - lse;
  log_t[row * DD + threadIdx.x] = lt;
  eT[row * DD + threadIdx.x] = (short)f2b(expf(lt));
}

// ---------- F2: fused y-GEMM + T-softmax (axis=d), high-TLP ----------
// grid (BATCH, 32): n-chunk 16. Block 256 thr / 4 waves; wave owns d in [w*64, w*64+64).
template <int LAST>
__global__ __launch_bounds__(256, 4) void k_f2(
    const short* __restrict__ Vt, const short* __restrict__ c2b,
    const float* __restrict__ x, const float* __restrict__ z,
    const float* __restrict__ log_s, float* __restrict__ log_t,
    short* __restrict__ eT, float* __restrict__ part,
    const float* __restrict__ P, int kiter) {
  __shared__ float red[96];
  const int b = blockIdx.x;
  const int n0 = blockIdx.y * 16;
  const int tid = threadIdx.x, wave = tid >> 6, lane = tid & 63;
  const int ln = lane & 15, kg = lane >> 4;
  const short* Av = Vt + (size_t)b * ((size_t)NN * DD);
  const short* Bv = c2b + (size_t)b * ((size_t)NN * NN);
  const size_t base = (size_t)b * ((size_t)NN * DD);

  const short* Ar[4];
#pragma unroll
  for (int i = 0; i < 4; ++i)
    Ar[i] = Av + (size_t)(wave * 64 + i * 16 + ln) * NN + kg * 8;
  const short* Br = Bv + (size_t)(n0 + ln) * NN + kg * 8;

  f32x4 acc[4];
#pragma unroll
  for (int i = 0; i < 4; ++i) acc[i] = (f32x4){0.f, 0.f, 0.f, 0.f};

  {
    bf16x8 a0[4], a1[4], b0, b1;
#pragma unroll
    for (int i = 0; i < 4; ++i) a0[i] = *(const bf16x8*)(Ar[i]);
    b0 = *(const bf16x8*)(Br);
#pragma unroll
    for (int k0 = 0; k0 < NN; k0 += 64) {
#pragma unroll
      for (int i = 0; i < 4; ++i) a1[i] = *(const bf16x8*)(Ar[i] + k0 + 32);
      b1 = *(const bf16x8*)(Br + k0 + 32);
#pragma unroll
      for (int i = 0; i < 4; ++i)
        acc[i] = __builtin_amdgcn_mfma_f32_16x16x32_bf16(a0[i], b0, acc[i], 0, 0, 0);
      if (k0 + 64 < NN) {
#pragma unroll
        for (int i = 0; i < 4; ++i) a0[i] = *(const bf16x8*)(Ar[i] + k0 + 64);
        b0 = *(const bf16x8*)(Br + k0 + 64);
      }
#pragma unroll
      for (int i = 0; i < 4; ++i)
        acc[i] = __builtin_amdgcn_mfma_f32_16x16x32_bf16(a1[i], b1, acc[i], 0, 0, 0);
    }
  }

  const float a0p_ = P[kiter], a1e = P[4 + kiter], rho = P[8 + kiter], mu = P[12 + kiter];
  const float inv = 1.0f / (rho + a0p_);
  const int c = n0 + ln;
#pragma unroll
  for (int i = 0; i < 4; ++i) {
    int r = wave * 64 + i * 16 + kg * 4;
    size_t idx = base + (size_t)c * DD + r;
    f32x4 xv = *(const f32x4*)&x[idx];
    f32x4 zv = *(const f32x4*)&z[idx];
    f32x4 lv = *(const f32x4*)&log_s[idx];
#pragma unroll
    for (int q = 0; q < 4; ++q)
      acc[i][q] = (xv[q] + a1e * acc[i][q] + zv[q] + rho * lv[q]) * inv;
  }
  // softmax over d (per col c): in-lane (i,q) -> kg (shfl 16,32) -> 4 waves (LDS)
  float m = -1e30f;
#pragma unroll
  for (int i = 0; i < 4; ++i)
#pragma unroll
    for (int q = 0; q < 4; ++q) m = fmaxf(m, acc[i][q]);
  m = fmaxf(m, __shfl_xor(m, 16));
  m = fmaxf(m, __shfl_xor(m, 32));
  if (lane < 16) red[wave * 16 + lane] = m;
  __syncthreads();
  float mc = fmaxf(fmaxf(red[ln], red[16 + ln]), fmaxf(red[32 + ln], red[48 + ln]));
  __syncthreads();
  float s = 0.f;
#pragma unroll
  for (int i = 0; i < 4; ++i)
#pragma unroll
    for (int q = 0; q < 4; ++q) s += expf(acc[i][q] - mc);
  s += __shfl_xor(s, 16);
  s += __shfl_xor(s, 32);
  if (lane < 16) red[wave * 16 + lane] = s;
  __syncthreads();
  float lse = mc + logf(red[ln] + red[16 + ln] + red[32 + ln] + red[48 + ln]);

  if (LAST == 0) {
#pragma unroll
    for (int i = 0; i < 4; ++i) {
      int r = wave * 64 + i * 16 + kg * 4;
      size_t idx = base + (size_t)c * DD + r;
      f32x4 lt;
      u16x4 et;
#pragma unroll
      for (int q = 0; q < 4; ++q) {
        float v = mu + acc[i][q] - lse;
        lt[q] = v;
        et[q] = f2b(expf(v));
      }
      *(f32x4*)&log_t[idx] = lt;
      *(u16x4*)&eT[idx] = et;
    }
  } else {
    const size_t pbase = ((size_t)b * 32 + blockIdx.y) * DD;
#pragma unroll
    for (int i = 0; i < 4; ++i) {
      int r = wave * 64 + i * 16 + kg * 4;
      size_t idx = base + (size_t)c * DD + r;
      f32x4 xv = *(const f32x4*)&x[idx];
      float p0 = expf(mu + acc[i][0] - lse) * xv[0];
      float p1 = expf(mu + acc[i][1] - lse) * xv[1];
      float p2 = expf(mu + acc[i][2] - lse) * xv[2];
      float p3 = expf(mu + acc[i][3] - lse) * xv[3];
#pragma unroll
      for (int o = 1; o < 16; o <<= 1) {
        p0 += __shfl_xor(p0, o);
        p1 += __shfl_xor(p1, o);
        p2 += __shfl_xor(p2, o);
        p3 += __shfl_xor(p3, o);
      }
      if (ln == 0) {
        part[pbase + r + 0] = p0;
        part[pbase + r + 1] = p1;
        part[pbase + r + 2] = p2;
        part[pbase + r + 3] = p3;
      }
    }
  }
}

// ---------- F3: fused y2-GEMM + S-softmax (axis=n) + dual z-update, high-TLP ----------
// grid (BATCH, 16): d-chunk 16. Block 512 thr / 8 waves; wave owns n in [w*64, w*64+64).
template <int ZFIRST>
__global__ __launch_bounds__(512, 4) void k_f3(
    const short* __restrict__ Vt, const short* __restrict__ c2b,
    const float* __restrict__ log_t, const short* __restrict__ eT,
    float* __restrict__ log_s, short* __restrict__ eS, float* __restrict__ z,
    const float* __restrict__ P, int kiter) {
  __shared__ float red[160];
  const int b = blockIdx.x;
  const int m0 = blockIdx.y * 16;
  const int tid = threadIdx.x, wave = tid >> 6, lane = tid & 63;
  const int ln = lane & 15, kg = lane >> 4;
  const short* Av = Vt + (size_t)b * ((size_t)NN * DD);
  const short* Bv = c2b + (size_t)b * ((size_t)NN * NN);
  const size_t base = (size_t)b * ((size_t)NN * DD);

  const short* Ar = Av + (size_t)(m0 + ln) * NN + kg * 8;
  const short* Br[4];
#pragma unroll
  for (int j = 0; j < 4; ++j)
    Br[j] = Bv + (size_t)(wave * 64 + j * 16 + ln) * NN + kg * 8;

  f32x4 acc[4];
#pragma unroll
  for (int j = 0; j < 4; ++j) acc[j] = (f32x4){0.f, 0.f, 0.f, 0.f};

  {
    bf16x8 a0, a1, b0[4], b1[4];
    a0 = *(const bf16x8*)(Ar);
#pragma unroll
    for (int j = 0; j < 4; ++j) b0[j] = *(const bf16x8*)(Br[j]);
#pragma unroll
    for (int k0 = 0; k0 < NN; k0 += 64) {
      a1 = *(const bf16x8*)(Ar + k0 + 32);
#pragma unroll
      for (int j = 0; j < 4; ++j) b1[j] = *(const bf16x8*)(Br[j] + k0 + 32);
#pragma unroll
      for (int j = 0; j < 4; ++j)
        acc[j] = __builtin_amdgcn_mfma_f32_16x16x32_bf16(a0, b0[j], acc[j], 0, 0, 0);
      if (k0 + 64 < NN) {
        a0 = *(const bf16x8*)(Ar + k0 + 64);
#pragma unroll
        for (int j = 0; j < 4; ++j) b0[j] = *(const bf16x8*)(Br[j] + k0 + 64);
      }
#pragma unroll
      for (int j = 0; j < 4; ++j)
        acc[j] = __builtin_amdgcn_mfma_f32_16x16x32_bf16(a1, b1[j], acc[j], 0, 0, 0);
    }
  }

  const float a1e = P[4 + kiter], rho = P[8 + kiter], eta = P[16 + kiter];
  const float invr = 1.0f / rho;
  const int r0 = m0 + kg * 4;
  f32x4 zreg[4];
#pragma unroll
  for (int j = 0; j < 4; ++j) {
    int c = wave * 64 + j * 16 + ln;
    size_t idx = base + (size_t)c * DD + r0;
    f32x4 lv = *(const f32x4*)&log_t[idx];
    if (ZFIRST) zreg[j] = (f32x4){0.f, 0.f, 0.f, 0.f};
    else zreg[j] = *(const f32x4*)&z[idx];
#pragma unroll
    for (int q = 0; q < 4; ++q)
      acc[j][q] = (a1e * acc[j][q] - zreg[j][q] + rho * lv[q]) * invr;
  }
  // softmax over n (per row r0+q): in-lane j -> ln (shfl 1..8) -> 8 waves (LDS)
  float pm[4];
#pragma unroll
  for (int q = 0; q < 4; ++q) {
    float m = fmaxf(fmaxf(acc[0][q], acc[1][q]), fmaxf(acc[2][q], acc[3][q]));
#pragma unroll
    for (int o = 1; o < 16; o <<= 1) m = fmaxf(m, __shfl_xor(m, o));
    pm[q] = m;
  }
  if (ln == 0) {
#pragma unroll
    for (int q = 0; q < 4; ++q) red[wave * 16 + kg * 4 + q] = pm[q];
  }
  __syncthreads();
  if (tid < 16) {
    float M = red[tid];
#pragma unroll
    for (int w = 1; w < 8; ++w) M = fmaxf(M, red[w * 16 + tid]);
    red[128 + tid] = M;
  }
  __syncthreads();
  float mc[4], psv[4];
#pragma unroll
  for (int q = 0; q < 4; ++q) {
    mc[q] = red[128 + kg * 4 + q];
    float s = expf(acc[0][q] - mc[q]) + expf(acc[1][q] - mc[q]) +
              expf(acc[2][q] - mc[q]) + expf(acc[3][q] - mc[q]);
#pragma unroll
    for (int o = 1; o < 16; o <<= 1) s += __shfl_xor(s, o);
    psv[q] = s;
  }
  __syncthreads();
  if (ln == 0) {
#pragma unroll
    for (int q = 0; q < 4; ++q) red[wave * 16 + kg * 4 + q] = psv[q];
  }
  __syncthreads();
  if (tid < 16) {
    float S = 0.f;
#pragma unroll
    for (int w = 0; w < 8; ++w) S += red[w * 16 + tid];
    red[144 + tid] = red[128 + tid] + logf(S);
  }
  __syncthreads();
  float lsev[4];
#pragma unroll
  for (int q = 0; q < 4; ++q) lsev[q] = red[144 + kg * 4 + q];

  // final: log_s, eS, z-update
#pragma unroll
  for (int j = 0; j < 4; ++j) {
    int c = wave * 64 + j * 16 + ln;
    size_t idx = base + (size_t)c * DD + r0;
    f32x4 ls, esf;
    u16x4 ev;
#pragma unroll
    for (int q = 0; q < 4; ++q) {
      float v = eta + acc[j][q] - lsev[q];
      ls[q] = v;
      float e = expf(v);
      esf[q] = e;
      ev[q] = f2b(e);
    }
    *(f32x4*)&log_s[idx] = ls;
    *(u16x4*)&eS[idx] = ev;
    u16x4 et = *(const u16x4*)&eT[idx];
    f32x4 zo;
#pragma unroll
    for (int q = 0; q < 4; ++q) zo[q] = zreg[j][q] + rho * (b2f(et[q]) - esf[q]);
    *(f32x4*)&z[idx] = zo;
  }
}

// ---------- final reduce: out[b][d] = D * sum over 32 partial chunks ----------
__global__ __launch_bounds__(256) void k_out2(const float* __restrict__ part,
                                              float* __restrict__ out) {
  int b = blockIdx.x, d = threadIdx.x;
  float acc = 0.0f;
#pragma unroll
  for (int c = 0; c < 32; ++c) acc += part[((size_t)b * 32 + c) * DD + d];
  out[(size_t)b * DD + d] = (float)DD * acc;
}

// ---------- launch ----------
extern "C" void kernel_launch(void* const* d_in, const int* in_sizes, int n_in,
                              void* d_out, int out_size, void* d_ws, size_t ws_size,
                              hipStream_t stream) {
  const float* x = (const float*)d_in[0];
  const float* a0p = (const float*)d_in[1];
  const float* a1p = (const float*)d_in[2];
  const float* a2p = (const float*)d_in[3];
  const float* a3p = (const float*)d_in[4];
  const float* rhop = (const float*)d_in[5];
  float* out = (float*)d_out;

  const size_t NE = (size_t)BATCH * NN * DD;
  const size_t NE_b = (size_t)NN * DD;
  const size_t C2_b = (size_t)NN * NN;
  const size_t C1_b = (size_t)DD * DD;

  float* fws = (float*)d_ws;
  float* log_t = fws;              // NE
  float* log_s = fws + NE;         // NE
  float* zb = fws + 2 * NE;        // NE
  float* part = fws + 3 * NE;      // B*32*DD = 262144
  float* r2 = part + 262144;       // B*N
  float* s1 = r2 + BATCH * NN;     // B*D
  float* P = s1 + BATCH * DD;      // 24
  unsigned* keys = (unsigned*)(P + 24);
  short* sws = (short*)(keys + 8);
  short* xb = sws;                 // NE (aliased: eS)
  short* xTb = sws + NE;           // NE (aliased: eT)
  short* eS = xb;
  short* eT = xTb;
  short* Vt = sws + 2 * NE;        // NE
  short* c1b = sws + 3 * NE;       // B*D*D
  short* c2b = c1b + (size_t)BATCH * C1_b;  // B*N*N

  k_prep<<<dim3(4, 8, BATCH), 256, 0, stream>>>(x, xb, xTb, keys);
  k_gemm<256, 0><<<dim3(BATCH, 8, 8), 256, 0, stream>>>(
      xb, NE_b, DD, xb, NE_b, DD, (void*)c2b, C2_b, NN, 1.0f / DD, keys + 1);
  k_gemm<512, 0><<<dim3(BATCH, 4, 4), 256, 0, stream>>>(
      xTb, NE_b, NN, xTb, NE_b, NN, (void*)c1b, C1_b, DD, 1.0f / NN, keys + 0);
  k_misc<<<6145, 256, 0, stream>>>(c2b, c1b, r2, s1, a0p, a1p, a2p, a3p, rhop, P, keys);

  // k = 0: rank-1 T-update, then S-half
  k_trow0<<<BATCH * NN, 256, 0, stream>>>(x, r2, s1, log_t, eT, P);
  k_gemm<256, 1><<<dim3(BATCH, 8, 4), 256, 0, stream>>>(
      eT, NE_b, DD, c1b, C1_b, DD, (void*)Vt, NE_b, NN, 1.0f, nullptr);
  k_f3<1><<<dim3(BATCH, 16), 512, 0, stream>>>(Vt, c2b, log_t, eT, log_s, eS, zb, P, 0);

  for (int k = 1; k <= 2; ++k) {
    k_gemm<256, 1><<<dim3(BATCH, 8, 4), 256, 0, stream>>>(
        eS, NE_b, DD, c1b, C1_b, DD, (void*)Vt, NE_b, NN, 1.0f, nullptr);
    k_f2<0><<<dim3(BATCH, 32), 256, 0, stream>>>(Vt, c2b, x, zb, log_s, log_t, eT,
                                                 nullptr, P, k);
    k_gemm<256, 1><<<dim3(BATCH, 8, 4), 256, 0, stream>>>(
        eT, NE_b, DD, c1b, C1_b, DD, (void*)Vt, NE_b, NN, 1.0f, nullptr);
    k_f3<0><<<dim3(BATCH, 16), 512, 0, stream>>>(Vt, c2b, log_t, eT, log_s, eS, zb, P, k);
  }

  // k = 3: only the T-half affects the output (tail-trim), fused with output partials
  k_gemm<256, 1><<<dim3(BATCH, 8, 4), 256, 0, stream>>>(
      eS, NE_b, DD, c1b, C1_b, DD, (void*)Vt, NE_b, NN, 1.0f, nullptr);
  k_f2<1><<<dim3(BATCH, 32), 256, 0, stream>>>(Vt, c2b, x, zb, log_s, log_t, eT,
                                               part, P, 3);
  k_out2<<<BATCH, 256, 0, stream>>>(part, out);
}

// Round 7
// 326.436 us; speedup vs baseline: 1.2663x; 1.2663x over previous
//
#include <hip/hip_runtime.h>
#include <math.h>

#define BATCH 32
#define NN 512
#define DD 256
#define NUMK 4

typedef __attribute__((ext_vector_type(8))) short bf16x8;
typedef __attribute__((ext_vector_type(4))) float f32x4;
typedef __attribute__((ext_vector_type(4))) unsigned short u16x4;

__device__ __forceinline__ float softplusf(float v) { return log1pf(expf(v)); }

__device__ __forceinline__ unsigned enc_key(float v) {
  unsigned u = __float_as_uint(v);
  return (u & 0x80000000u) ? ~u : (u | 0x80000000u);
}
__device__ __forceinline__ float dec_key(unsigned k) {
  return (k & 0x80000000u) ? __uint_as_float(k & 0x7fffffffu) : __uint_as_float(~k);
}
__device__ __forceinline__ unsigned short f2b(float f) {
  unsigned u = __float_as_uint(f);
  unsigned r = (u + 0x7fffu + ((u >> 16) & 1u)) >> 16;
  return (unsigned short)r;
}
__device__ __forceinline__ float b2f(unsigned short h) {
  return __uint_as_float(((unsigned)h) << 16);
}

#define GLDS(gp, lp)                                                   \
  __builtin_amdgcn_global_load_lds(                                    \
      (__attribute__((address_space(1))) void*)(void*)(gp),            \
      (__attribute__((address_space(3))) void*)(lp), 16, 0, 0)

// ---------- prep: xb=bf16(x)[n][d], xTb=bf16(x^T)[d][n], xT=f32(x^T); zero keys ----------
__global__ __launch_bounds__(256) void k_prep(const float* __restrict__ x,
                                              short* __restrict__ xb,
                                              short* __restrict__ xTb,
                                              float* __restrict__ xT,
                                              unsigned* keys) {
  __shared__ float t[64][65];
  int b = blockIdx.z, n0 = blockIdx.y * 64, d0 = blockIdx.x * 64;
  if (blockIdx.x == 0 && blockIdx.y == 0 && blockIdx.z == 0 && threadIdx.x == 0) {
    keys[0] = 0u; keys[1] = 0u;
  }
  const float* X = x + (size_t)b * NN * DD;
  int col = threadIdx.x & 63, rr = threadIdx.x >> 6;
#pragma unroll
  for (int s = 0; s < 16; ++s) {
    int row = s * 4 + rr;
    float v = X[(size_t)(n0 + row) * DD + d0 + col];
    t[row][col] = v;
    xb[(size_t)b * NN * DD + (size_t)(n0 + row) * DD + d0 + col] = (short)f2b(v);
  }
  __syncthreads();
#pragma unroll
  for (int s = 0; s < 16; ++s) {
    int row = s * 4 + rr;  // d within tile
    float v = t[col][row];
    size_t idx = (size_t)b * DD * NN + (size_t)(d0 + row) * NN + n0 + col;
    xTb[idx] = (short)f2b(v);
    xT[idx] = v;
  }
}

// ---------- GEMM: C[m][c] = sum_k A[m][k]*B[c][k]; 64x64 tile, BK=64, swizzled LDS ----------
// grid (BATCH, mtiles, ctiles).
// OUTK 0: bf16 transposed store out[c*ldo+m], *scale, fused atomicMax (Gram; symmetric out)
// OUTK 1: bf16 natural store out[m*ldo+c]                              (W = c2 @ E)
template <int K, int OUTK>
__global__ __launch_bounds__(256) void k_gemm(
    const short* __restrict__ A, size_t sA, int lda,
    const short* __restrict__ Bp, size_t sB, int ldb,
    void* __restrict__ outp, size_t sO, int ldo,
    float scale, unsigned* maxslot) {
  __shared__ short As[64 * 64];
  __shared__ short Bs[64 * 64];
  const int b = blockIdx.x;
  const int m0 = blockIdx.y * 64, n0 = blockIdx.z * 64;
  const int tid = threadIdx.x, wave = tid >> 6, lane = tid & 63;
  const int ln = lane & 15, kg = lane >> 4;
  const int wr = (wave >> 1) * 32, wc = (wave & 1) * 32;
  const short* Ab = A + (size_t)b * sA;
  const short* Bb = Bp + (size_t)b * sB;
  const int srow = lane >> 3;
  const int sslot = lane & 7;

  f32x4 acc[2][2];
#pragma unroll
  for (int i = 0; i < 2; ++i)
#pragma unroll
    for (int j = 0; j < 2; ++j) acc[i][j] = (f32x4){0.f, 0.f, 0.f, 0.f};

  for (int k0 = 0; k0 < K; k0 += 64) {
    __syncthreads();
#pragma unroll
    for (int p = 0; p < 2; ++p) {
      int row = p * 32 + wave * 8 + srow;
      int sg = sslot ^ (row & 7);
      GLDS(Ab + (size_t)(m0 + row) * lda + k0 + sg * 8, &As[(p * 32 + wave * 8) * 64]);
      GLDS(Bb + (size_t)(n0 + row) * ldb + k0 + sg * 8, &Bs[(p * 32 + wave * 8) * 64]);
    }
    __syncthreads();
    bf16x8 af[2][2], bfr[2][2];
#pragma unroll
    for (int i = 0; i < 2; ++i)
#pragma unroll
      for (int kk = 0; kk < 2; ++kk) {
        int rowA = wr + i * 16 + ln;
        af[i][kk] = *(const bf16x8*)&As[rowA * 64 + (((kk * 4 + kg) ^ (rowA & 7)) * 8)];
        int rowB = wc + i * 16 + ln;
        bfr[i][kk] = *(const bf16x8*)&Bs[rowB * 64 + (((kk * 4 + kg) ^ (rowB & 7)) * 8)];
      }
#pragma unroll
    for (int kk = 0; kk < 2; ++kk)
#pragma unroll
      for (int i = 0; i < 2; ++i)
#pragma unroll
        for (int j = 0; j < 2; ++j)
          acc[i][j] = __builtin_amdgcn_mfma_f32_16x16x32_bf16(af[i][kk], bfr[j][kk],
                                                              acc[i][j], 0, 0, 0);
  }

  unsigned short* ot = (unsigned short*)outp + (size_t)b * sO;
  if (OUTK == 0) {
    float tmax = -1e30f;
#pragma unroll
    for (int i = 0; i < 2; ++i) {
      int r = m0 + wr + i * 16 + kg * 4;
#pragma unroll
      for (int j = 0; j < 2; ++j) {
        int c = n0 + wc + j * 16 + ln;
        u16x4 pk;
#pragma unroll
        for (int q = 0; q < 4; ++q) {
          float v = acc[i][j][q] * scale;
          tmax = fmaxf(tmax, v);
          pk[q] = f2b(v);
        }
        *(u16x4*)&ot[(size_t)c * ldo + r] = pk;
      }
    }
#pragma unroll
    for (int o = 32; o > 0; o >>= 1) tmax = fmaxf(tmax, __shfl_xor(tmax, o));
    __syncthreads();
    float* smf = (float*)As;
    if (lane == 0) smf[wave] = tmax;
    __syncthreads();
    if (tid == 0)
      atomicMax(maxslot, enc_key(fmaxf(fmaxf(smf[0], smf[1]), fmaxf(smf[2], smf[3]))));
  } else {
    // natural store: coalesced across 16 ln-lanes
#pragma unroll
    for (int i = 0; i < 2; ++i)
#pragma unroll
      for (int j = 0; j < 2; ++j) {
        int c = n0 + wc + j * 16 + ln;
#pragma unroll
        for (int q = 0; q < 4; ++q) {
          int r = m0 + wr + i * 16 + kg * 4 + q;
          ot[(size_t)r * ldo + c] = f2b(acc[i][j][q]);
        }
      }
  }
}

// ---------- y-GEMM: yT[d'][n] = epi(sum_d c1[d'][d] * W[n][d]) ; K=256 fixed ----------
// MODE 2: yT = (xT + a1e*acc + zT + rho*log_sT)/(rho+a0)
// MODE 3: yT = (a1e*acc - zT + rho*log_tT)/rho           (ZFIRST: zT==0)
template <int MODE, int ZFIRST>
__global__ __launch_bounds__(256) void k_ygemm(
    const short* __restrict__ c1b, const short* __restrict__ W,
    const float* __restrict__ xT, const float* __restrict__ zT,
    const float* __restrict__ Lt, float* __restrict__ yT,
    const float* __restrict__ P, int kiter) {
  __shared__ short As[64 * 64];
  __shared__ short Bs[64 * 64];
  const int b = blockIdx.x;
  const int m0 = blockIdx.y * 64, n0 = blockIdx.z * 64;
  const int tid = threadIdx.x, wave = tid >> 6, lane = tid & 63;
  const int ln = lane & 15, kg = lane >> 4;
  const int wr = (wave >> 1) * 32, wc = (wave & 1) * 32;
  const short* Ab = c1b + (size_t)b * ((size_t)DD * DD);
  const short* Bb = W + (size_t)b * ((size_t)NN * DD);
  const size_t base = (size_t)b * ((size_t)NN * DD);
  const int srow = lane >> 3;
  const int sslot = lane & 7;

  f32x4 acc[2][2];
#pragma unroll
  for (int i = 0; i < 2; ++i)
#pragma unroll
    for (int j = 0; j < 2; ++j) acc[i][j] = (f32x4){0.f, 0.f, 0.f, 0.f};

  for (int k0 = 0; k0 < DD; k0 += 64) {
    __syncthreads();
#pragma unroll
    for (int p = 0; p < 2; ++p) {
      int row = p * 32 + wave * 8 + srow;
      int sg = sslot ^ (row & 7);
      GLDS(Ab + (size_t)(m0 + row) * DD + k0 + sg * 8, &As[(p * 32 + wave * 8) * 64]);
      GLDS(Bb + (size_t)(n0 + row) * DD + k0 + sg * 8, &Bs[(p * 32 + wave * 8) * 64]);
    }
    __syncthreads();
    bf16x8 af[2][2], bfr[2][2];
#pragma unroll
    for (int i = 0; i < 2; ++i)
#pragma unroll
      for (int kk = 0; kk < 2; ++kk) {
        int rowA = wr + i * 16 + ln;
        af[i][kk] = *(const bf16x8*)&As[rowA * 64 + (((kk * 4 + kg) ^ (rowA & 7)) * 8)];
        int rowB = wc + i * 16 + ln;
        bfr[i][kk] = *(const bf16x8*)&Bs[rowB * 64 + (((kk * 4 + kg) ^ (rowB & 7)) * 8)];
      }
#pragma unroll
    for (int kk = 0; kk < 2; ++kk)
#pragma unroll
      for (int i = 0; i < 2; ++i)
#pragma unroll
        for (int j = 0; j < 2; ++j)
          acc[i][j] = __builtin_amdgcn_mfma_f32_16x16x32_bf16(af[i][kk], bfr[j][kk],
                                                              acc[i][j], 0, 0, 0);
  }

  const float a0 = P[kiter], a1e = P[4 + kiter], rho = P[8 + kiter];
  const float inv = (MODE == 2) ? 1.0f / (rho + a0) : 1.0f / rho;
#pragma unroll
  for (int i = 0; i < 2; ++i)
#pragma unroll
    for (int j = 0; j < 2; ++j) {
      int c = n0 + wc + j * 16 + ln;
#pragma unroll
      for (int q = 0; q < 4; ++q) {
        int r = m0 + wr + i * 16 + kg * 4 + q;
        size_t idx = base + (size_t)r * NN + c;
        float o;
        if (MODE == 2) {
          o = (xT[idx] + a1e * acc[i][j][q] + zT[idx] + rho * Lt[idx]) * inv;
        } else {
          float zv = ZFIRST ? 0.0f : zT[idx];
          o = (a1e * acc[i][j][q] - zv + rho * Lt[idx]) * inv;
        }
        yT[idx] = o;
      }
    }
}

// ---------- misc: row sums of c2/c1 + scalar params ----------
__global__ __launch_bounds__(256) void k_misc(const short* __restrict__ c2b,
                                              const short* __restrict__ c1b,
                                              float* __restrict__ r2,
                                              float* __restrict__ s1,
                                              const float* a0p, const float* a1p,
                                              const float* a2p, const float* a3p,
                                              const float* rhop, float* P,
                                              const unsigned* keys) {
  int bid = blockIdx.x;
  int lane = threadIdx.x & 63;
  if (bid < 4096) {
    int row = bid * 4 + (threadIdx.x >> 6);
    bf16x8 v = *(const bf16x8*)(c2b + (size_t)row * 512 + lane * 8);
    float s = 0.f;
#pragma unroll
    for (int q = 0; q < 8; ++q) s += b2f((unsigned short)v[q]);
#pragma unroll
    for (int o = 32; o > 0; o >>= 1) s += __shfl_xor(s, o);
    if (lane == 0) r2[row] = s;
  } else if (bid < 6144) {
    int row = (bid - 4096) * 4 + (threadIdx.x >> 6);
    u16x4 v = *(const u16x4*)(c1b + (size_t)row * 256 + lane * 4);
    float s = 0.f;
#pragma unroll
    for (int q = 0; q < 4; ++q) s += b2f(v[q]);
#pragma unroll
    for (int o = 32; o > 0; o >>= 1) s += __shfl_xor(s, o);
    if (lane == 0) s1[row] = s;
  } else if (threadIdx.x == 0) {
    float M1 = dec_key(keys[0]);
    float M2 = dec_key(keys[1]);
    float lq0 = logf(1.0f / NN + 1e-8f);
    float lp0 = logf(1.0f / DD + 1e-8f);
    float mu = lq0, eta = lp0, z1 = 0.f, z2 = 0.f;
    for (int k = 0; k < NUMK; ++k) {
      float a0 = softplusf(a0p[k]), a1 = softplusf(a1p[k]);
      float a2 = softplusf(a2p[k]), a3 = softplusf(a3p[k]);
      float rho = softplusf(rhop[k]);
      P[0 + k] = a0;
      P[4 + k] = a1 / (M1 * M2);
      P[8 + k] = rho;
      P[12 + k] = mu;
      P[16 + k] = eta;
      float t1 = mu;
      mu = (a2 * lq0 + rho * t1 - z1) / (a2 + rho);
      z1 += rho * (expf(mu) - expf(t1));
      float s1v = eta;
      eta = (a3 * lp0 + rho * s1v - z2) / (a3 + rho);
      z2 += rho * (expf(eta) - expf(s1v));
    }
  }
}

// ---------- T-softmax (axis=d) on yT columns; one column per 8-lane group ----------
// grid (BATCH, 8), block 512: nl = tid>>3 (64 n), ds = tid&7; thread scans 32 d-values.
// FIRST: y built from xT + rank-1 gw (k=0 shortcut); softmax shift drops rho*c0 term.
template <int FIRST>
__global__ __launch_bounds__(512) void k_tsm(
    const float* __restrict__ yT, const float* __restrict__ xT,
    const float* __restrict__ r2, const float* __restrict__ s1,
    float* __restrict__ log_tT, short* __restrict__ eTT,
    const float* __restrict__ P, int kiter) {
  const int b = blockIdx.x, n0 = blockIdx.y * 64;
  const int nl = threadIdx.x >> 3, ds = threadIdx.x & 7;
  const int n = n0 + nl;
  const size_t base = (size_t)b * ((size_t)NN * DD);
  float y[32];
  float g = 0.f, inv = 1.f;
  if (FIRST) {
    const float c0 = logf(1.0f / NN + 1e-8f) + logf(1.0f / DD + 1e-8f);
    g = P[4] * expf(c0) * r2[b * NN + n];
    inv = 1.0f / (P[8] + P[0]);
  }
  const float* src = FIRST ? xT : yT;
  float m = -1e30f;
#pragma unroll
  for (int dk = 0; dk < 32; ++dk) {
    int d = dk * 8 + ds;
    float v = src[base + (size_t)d * NN + n];
    if (FIRST) v = (v + g * s1[b * DD + d]) * inv;
    y[dk] = v;
    m = fmaxf(m, v);
  }
  m = fmaxf(m, __shfl_xor(m, 1));
  m = fmaxf(m, __shfl_xor(m, 2));
  m = fmaxf(m, __shfl_xor(m, 4));
  float s = 0.f;
#pragma unroll
  for (int dk = 0; dk < 32; ++dk) s += expf(y[dk] - m);
  s += __shfl_xor(s, 1);
  s += __shfl_xor(s, 2);
  s += __shfl_xor(s, 4);
  const float lse = m + logf(s);
  const float mu = P[12 + kiter];
#pragma unroll
  for (int dk = 0; dk < 32; ++dk) {
    int d = dk * 8 + ds;
    size_t idx = base + (size_t)d * NN + n;
    float lt = mu + y[dk] - lse;
    log_tT[idx] = lt;
    eTT[idx] = (short)f2b(expf(lt));
  }
}

// ---------- S-softmax (axis=n) rows of y2T + eS + dual z-update ----------
// grid (BATCH, 8), block 256 = 4 waves x 8 rows; row = 512 floats = lane*8.
template <int ZFIRST>
__global__ __launch_bounds__(256) void k_ssm(
    const float* __restrict__ y2T, const short* __restrict__ eTT,
    float* __restrict__ log_sT, short* __restrict__ eST, float* __restrict__ zT,
    const float* __restrict__ P, int kiter) {
  const int b = blockIdx.x, d0 = blockIdx.y * 32;
  const int wave = threadIdx.x >> 6, lane = threadIdx.x & 63;
  const size_t base = (size_t)b * ((size_t)NN * DD);
  const float rho = P[8 + kiter], eta = P[16 + kiter];
#pragma unroll
  for (int rr = 0; rr < 8; ++rr) {
    int row = d0 + wave * 8 + rr;
    size_t roff = base + (size_t)row * NN + lane * 8;
    f32x4 v0 = *(const f32x4*)&y2T[roff];
    f32x4 v1 = *(const f32x4*)&y2T[roff + 4];
    float m = fmaxf(fmaxf(fmaxf(v0[0], v0[1]), fmaxf(v0[2], v0[3])),
                    fmaxf(fmaxf(v1[0], v1[1]), fmaxf(v1[2], v1[3])));
#pragma unroll
    for (int o = 1; o < 64; o <<= 1) m = fmaxf(m, __shfl_xor(m, o));
    float s = 0.f;
#pragma unroll
    for (int q = 0; q < 4; ++q) s += expf(v0[q] - m) + expf(v1[q] - m);
#pragma unroll
    for (int o = 1; o < 64; o <<= 1) s += __shfl_xor(s, o);
    float lse = m + logf(s);
    f32x4 ls0, ls1, es0, es1;
    u16x4 ev0, ev1;
#pragma unroll
    for (int q = 0; q < 4; ++q) {
      ls0[q] = eta + v0[q] - lse;
      es0[q] = expf(ls0[q]);
      ev0[q] = f2b(es0[q]);
      ls1[q] = eta + v1[q] - lse;
      es1[q] = expf(ls1[q]);
      ev1[q] = f2b(es1[q]);
    }
    *(f32x4*)&log_sT[roff] = ls0;
    *(f32x4*)&log_sT[roff + 4] = ls1;
    *(u16x4*)&eST[roff] = ev0;
    *(u16x4*)&eST[roff + 4] = ev1;
    bf16x8 et = *(const bf16x8*)&eTT[roff];
    f32x4 z0, z1;
    if (ZFIRST) {
      z0 = (f32x4){0.f, 0.f, 0.f, 0.f};
      z1 = z0;
    } else {
      z0 = *(const f32x4*)&zT[roff];
      z1 = *(const f32x4*)&zT[roff + 4];
    }
#pragma unroll
    for (int q = 0; q < 4; ++q) {
      z0[q] += rho * (b2f((unsigned short)et[q]) - es0[q]);
      z1[q] += rho * (b2f((unsigned short)et[4 + q]) - es1[q]);
    }
    *(f32x4*)&zT[roff] = z0;
    *(f32x4*)&zT[roff + 4] = z1;
  }
}

// ---------- output: out[b][d'] = D * sum_n xT * exp(log_tT), row-reduce ----------
__global__ __launch_bounds__(256) void k_out(const float* __restrict__ xT,
                                             const float* __restrict__ log_tT,
                                             float* __restrict__ out) {
  const int b = blockIdx.x, d0 = blockIdx.y * 32;
  const int wave = threadIdx.x >> 6, lane = threadIdx.x & 63;
  const size_t base = (size_t)b * ((size_t)NN * DD);
#pragma unroll
  for (int rr = 0; rr < 8; ++rr) {
    int row = d0 + wave * 8 + rr;
    size_t roff = base + (size_t)row * NN + lane * 8;
    f32x4 x0 = *(const f32x4*)&xT[roff];
    f32x4 x1 = *(const f32x4*)&xT[roff + 4];
    f32x4 l0 = *(const f32x4*)&log_tT[roff];
    f32x4 l1 = *(const f32x4*)&log_tT[roff + 4];
    float acc = 0.f;
#pragma unroll
    for (int q = 0; q < 4; ++q) acc += x0[q] * expf(l0[q]) + x1[q] * expf(l1[q]);
#pragma unroll
    for (int o = 1; o < 64; o <<= 1) acc += __shfl_xor(acc, o);
    if (lane == 0) out[(size_t)b * DD + row] = (float)DD * acc;
  }
}

// ---------- launch ----------
extern "C" void kernel_launch(void* const* d_in, const int* in_sizes, int n_in,
                              void* d_out, int out_size, void* d_ws, size_t ws_size,
                              hipStream_t stream) {
  const float* x = (const float*)d_in[0];
  const float* a0p = (const float*)d_in[1];
  const float* a1p = (const float*)d_in[2];
  const float* a2p = (const float*)d_in[3];
  const float* a3p = (const float*)d_in[4];
  const float* rhop = (const float*)d_in[5];
  float* out = (float*)d_out;

  const size_t NE = (size_t)BATCH * NN * DD;
  const size_t NE_b = (size_t)NN * DD;
  const size_t C2_b = (size_t)NN * NN;
  const size_t C1_b = (size_t)DD * DD;

  float* fws = (float*)d_ws;
  float* xT = fws;                 // NE (f32 x^T, d-major)
  float* yT = fws + NE;            // NE (y / y2 scratch, d-major)
  float* log_tT = fws + 2 * NE;    // NE
  float* log_sT = fws + 3 * NE;    // NE
  float* zT = fws + 4 * NE;        // NE
  float* r2 = fws + 5 * NE;        // B*N
  float* s1 = r2 + BATCH * NN;     // B*D
  float* P = s1 + BATCH * DD;      // 24
  unsigned* keys = (unsigned*)(P + 24);
  short* sws = (short*)(keys + 8);
  short* xb = sws;                 // NE (n-major bf16; dead after gram -> alias eST)
  short* xTb = sws + NE;           // NE (d-major bf16; dead after gram -> alias eTT)
  short* eST = xb;
  short* eTT = xTb;
  short* W = sws + 2 * NE;         // NE (n-major [n][d])
  short* c1b = sws + 3 * NE;       // B*D*D
  short* c2b = c1b + (size_t)BATCH * C1_b;  // B*N*N

  k_prep<<<dim3(4, 8, BATCH), 256, 0, stream>>>(x, xb, xTb, xT, keys);
  // c2 = x x^T / D  (K=256), transposed store (symmetric)
  k_gemm<256, 0><<<dim3(BATCH, 8, 8), 256, 0, stream>>>(
      xb, NE_b, DD, xb, NE_b, DD, (void*)c2b, C2_b, NN, 1.0f / DD, keys + 1);
  // c1 = x^T x / N  (K=512)
  k_gemm<512, 0><<<dim3(BATCH, 4, 4), 256, 0, stream>>>(
      xTb, NE_b, NN, xTb, NE_b, NN, (void*)c1b, C1_b, DD, 1.0f / NN, keys + 0);
  k_misc<<<6145, 256, 0, stream>>>(c2b, c1b, r2, s1, a0p, a1p, a2p, a3p, rhop, P, keys);

  // k = 0: rank-1 T-update (fused in k_tsm<1>), then S-half
  k_tsm<1><<<dim3(BATCH, 8), 512, 0, stream>>>(yT, xT, r2, s1, log_tT, eTT, P, 0);
  k_gemm<512, 1><<<dim3(BATCH, 8, 4), 256, 0, stream>>>(
      c2b, C2_b, NN, eTT, NE_b, NN, (void*)W, NE_b, DD, 1.0f, nullptr);
  k_ygemm<3, 1><<<dim3(BATCH, 4, 8), 256, 0, stream>>>(c1b, W, xT, zT, log_tT, yT, P, 0);
  k_ssm<1><<<dim3(BATCH, 8), 256, 0, stream>>>(yT, eTT, log_sT, eST, zT, P, 0);

  for (int k = 1; k <= 2; ++k) {
    k_gemm<512, 1><<<dim3(BATCH, 8, 4), 256, 0, stream>>>(
        c2b, C2_b, NN, eST, NE_b, NN, (void*)W, NE_b, DD, 1.0f, nullptr);
    k_ygemm<2, 0><<<dim3(BATCH, 4, 8), 256, 0, stream>>>(c1b, W, xT, zT, log_sT, yT, P, k);
    k_tsm<0><<<dim3(BATCH, 8), 512, 0, stream>>>(yT, xT, r2, s1, log_tT, eTT, P, k);
    k_gemm<512, 1><<<dim3(BATCH, 8, 4), 256, 0, stream>>>(
        c2b, C2_b, NN, eTT, NE_b, NN, (void*)W, NE_b, DD, 1.0f, nullptr);
    k_ygemm<3, 0><<<dim3(BATCH, 4, 8), 256, 0, stream>>>(c1b, W, xT, zT, log_tT, yT, P, k);
    k_ssm<0><<<dim3(BATCH, 8), 256, 0, stream>>>(yT, eTT, log_sT, eST, zT, P, k);
  }

  // k = 3: only the T-half affects the output (tail-trim)
  k_gemm<512, 1><<<dim3(BATCH, 8, 4), 256, 0, stream>>>(
      c2b, C2_b, NN, eST, NE_b, NN, (void*)W, NE_b, DD, 1.0f, nullptr);
  k_ygemm<2, 0><<<dim3(BATCH, 4, 8), 256, 0, stream>>>(c1b, W, xT, zT, log_sT, yT, P, 3);
  k_tsm<0><<<dim3(BATCH, 8), 512, 0, stream>>>(yT, xT, r2, s1, log_tT, eTT, P, 3);
  k_out<<<dim3(BATCH, 8), 256, 0, stream>>>(xT, log_tT, out);
}